// Round 15
// baseline (2625.587 us; speedup 1.0000x reference)
//
#include <hip/hip_runtime.h>
#include <hip/hip_bf16.h>

// ---------------------------------------------------------------------------
// Persistent fused 2-layer GRU + head for MI355X (gfx950).
//
// R23 -> R24 (post-mortem: R23's two micro-levers both failed (2345 steady
// vs R20's 2135): 3-deep pipe didn't pay, sc1 post slowed detection. Rule
// fires: the 4-wave/1-per-SIMD structure is at its floor -- every load
// stall idles a SIMD. R24 = R20's proven protocol + 8 waves (2/SIMD),
// splitting each role's K across same-SIMD pairs):
//  * 512 threads, 8 waves. Pairs: (w0,w4)=L0rt0, (w2,w6)=L0rt1,
//    (w1,w5)=L1h, (w3,w7)=L1x. Lead kc0-7 (+x), partner kc8-15.
//  * Polls: LEADS ONLY (w0,w2,w1,w3 -- exactly R20's 4 streams; R21/22
//    proved poll batching/throttling matters). Partners gate on an LDS
//    mailbox their lead bumps post-poll (LDS RT, no TCC traffic).
//  * L0 pairs: partner writes partials + lgkmcnt(0) + pd word; lead spins
//    pd, combines, epilogue, stores, posts flag0 PRE-P (keeps R20's early
//    h0 post). L1 partials ride P (like R20's part). All partial buffers
//    double-buffered by s&1; WAR distance-2 ordered via lead program order
//    (read -> own flag post -> next poll -> mailbox bump). Audited.
//  * buffer_inv per wave at own s%8==0 after its gate (R20 budget).
//    Plain write-through posts, sc1 read-only polls, 2-deep vmcnt pipes.
//  * Fallback: leads run R20's full-K bodies; partners idle (2 barriers).
// ---------------------------------------------------------------------------

namespace {
constexpr int kB  = 256;   // batch
constexpr int kT  = 512;   // time steps
constexpr int kF  = 32;    // input features
constexpr int kH  = 512;   // hidden
constexpr int kE  = 32;    // embed dim
constexpr int kPD = 30;    // predict days

constexpr int GBLK = 256;  // 8 XCD groups x 32 hidden slots, 1 block/CU
constexpr int NTHR = 512;  // 8 waves (2 per SIMD)
constexpr int RG   = 32;   // batch rows per group
constexpr int HB   = 16;   // hidden cols per block

constexpr int IMG  = kB * kH * 2;  // 256 KiB per h image (one step)
constexpr int RING = 8;            // ring depth (address reuse period)

// LDS layout (bytes). Partial buffers double-buffered by s&1.
constexpr int PB0_OFF = 0;       // pair0: 2 x 3KB  (3 gates x 64 x f32x4)
constexpr int PB2_OFF = 8192;    // pair2: 2 x 3KB
constexpr int PB1_OFF = 16384;   // w5:    2 x 6KB  (2rt x 3 x 64 x f32x4)
constexpr int PB3_OFF = 32768;   // w3,w7: 2 x 2 x 6KB
constexpr int HS_OFF  = 61440;   // handshake words, 128B apart
constexpr int LDSB    = 98304;   // pins 1 block/CU
static_assert(LDSB <= 160 * 1024, "LDS overflow");

// ws layout (bytes)
constexpr size_t WS_CNT   = 0;        // 8 per-XCD counters, 128B apart
constexpr size_t WS_TOTAL = 1024;     // arrival counter
constexpr size_t WS_FB    = 1152;     // fallback flag
constexpr size_t WS_FLG1  = 2048;     // 8 groups x 32 u32 (128B stride)
constexpr size_t WS_FLG0  = 4096;     // 8 groups x 64 u32 (256B stride)
constexpr size_t WS_H0B   = 65536;                          // RING*IMG
constexpr size_t WS_H1B   = WS_H0B + (size_t)RING * IMG;    // RING*IMG
constexpr size_t WS_H1F   = WS_H1B + (size_t)RING * IMG;    // B*H f32
constexpr size_t WS_INIT  = WS_H1F;   // zero [0, WS_H1F)

typedef __bf16 bf16_t;
typedef __bf16 bf16x8 __attribute__((ext_vector_type(8)));
typedef float  f32x4  __attribute__((ext_vector_type(4)));

#define MFMA __builtin_amdgcn_mfma_f32_16x16x32_bf16
#define LDSF4(p) (*(__attribute__((address_space(3))) f32x4*)(p))
#define LDSVU(p) (*(volatile __attribute__((address_space(3))) unsigned*)(p))

// counted vmcnt wait + scheduler fence (rule #18)
#define WAITVM(N)                                              \
  do {                                                         \
    asm volatile("s_waitcnt vmcnt(" #N ")" ::: "memory");      \
    __builtin_amdgcn_sched_barrier(0);                         \
  } while (0)

__device__ __forceinline__ float sigmoid_f(float x) {
  return 1.f / (1.f + __expf(-x));
}
__device__ __forceinline__ float tanh_f(float x) {
  float a = fabsf(x);
  float e = __expf(-2.f * a);
  float t = (1.f - e) / (1.f + e);
  return copysignf(t, x);
}

// Plain (L1-allocating) 16B load, NOT waited (caller manages vmcnt).
__device__ __forceinline__ bf16x8 ld16a(const char* p) {
  bf16x8 v;
  asm volatile("global_load_dwordx4 %0, %1, off"
               : "=v"(v) : "v"(p) : "memory");
  return v;
}

// 8 consecutive f32 -> bf16x8 fragment
__device__ __forceinline__ bf16x8 fragf(const float* p) {
  bf16x8 t;
#pragma unroll
  for (int j = 0; j < 8; ++j) t[j] = (bf16_t)p[j];
  return t;
}

// MALL-coherent primitives (fallback path only)
__device__ __forceinline__ bf16x8 ld16_mall(const bf16_t* p) {
  const unsigned long long* q = (const unsigned long long*)p;
  unsigned long long lo =
      __hip_atomic_load(q, __ATOMIC_RELAXED, __HIP_MEMORY_SCOPE_AGENT);
  unsigned long long hi =
      __hip_atomic_load(q + 1, __ATOMIC_RELAXED, __HIP_MEMORY_SCOPE_AGENT);
  union { unsigned long long u[2]; bf16x8 v; } x;
  x.u[0] = lo; x.u[1] = hi;
  return x.v;
}

__device__ __forceinline__ void st2_mall(bf16_t* p, float v) {
  bf16_t b = (bf16_t)v;
  unsigned short bits = __builtin_bit_cast(unsigned short, b);
  __hip_atomic_store((unsigned short*)p, bits, __ATOMIC_RELAXED,
                     __HIP_MEMORY_SCOPE_AGENT);
}
template <bool XL>
__device__ __forceinline__ void st2x(bf16_t* p, float v) {
  if constexpr (XL) *p = (bf16_t)v;
  else st2_mall(p, v);
}

__device__ __forceinline__ void drain_stores() {
  asm volatile("s_waitcnt vmcnt(0)" ::: "memory");
}

// Device-scope (sc1) 4B READ-ONLY flag load (R20-proven).
__device__ __forceinline__ unsigned ld_flag_sc1(const unsigned* p) {
  unsigned v;
  asm volatile("global_load_dword %0, %1, off sc1\n\ts_waitcnt vmcnt(0)"
               : "=v"(v) : "v"(p) : "memory");
  return v;
}

// Poll `base[idx]` until all participating lanes see >= tgt.
template <bool XL>
__device__ __forceinline__ void poll_flags(const unsigned* base, int idx,
                                           unsigned tgt) {
  const unsigned* fp = base + idx;
  long guard = 0;
  if constexpr (XL) {
    for (;;) {
      unsigned v = ld_flag_sc1(fp);
      if (__all((int)(v >= tgt))) break;
      if (++guard > (1L << 22)) break;  // co-residency guaranteed
    }
  } else {
    for (;;) {
      unsigned v = __hip_atomic_load(fp, __ATOMIC_RELAXED,
                                     __HIP_MEMORY_SCOPE_AGENT);
      if (__all((int)(v >= tgt))) break;
      __builtin_amdgcn_s_sleep(1);  // emergency path only
      if (++guard > (1L << 20)) break;
    }
  }
}

// Plain write-through post (R20-proven: fastest observable by sc1 pollers).
template <bool XL>
__device__ __forceinline__ void flag_post(unsigned* p, unsigned tgt) {
  if constexpr (XL) {
    *(volatile unsigned*)p = tgt;
  } else {
    __hip_atomic_store(p, tgt, __ATOMIC_RELAXED, __HIP_MEMORY_SCOPE_AGENT);
  }
}

// LDS word poll (uniform address, broadcast read).
__device__ __forceinline__ void lds_poll(unsigned* p, unsigned tgt) {
  long guard = 0;
  while (LDSVU(p) < tgt) {
    if (++guard > (1L << 22)) break;
  }
  asm volatile("" ::: "memory");
}
}  // namespace

// Fragment-major image layout: byte off = ((g*2+rt)*16 + kc)*1024 + lane*16
// Ring: image for step s lives at slot (s & 7) * IMG.

// half-K pipeline macros
#define HL0_ISSUE(buf, base)                                        \
  _Pragma("unroll") for (int j = 0; j < 4; ++j)                     \
      buf[j] = ld16a(hsrc + (base + j) * 1024)
#define HL0_MFMA(w, buf, base)                                      \
  _Pragma("unroll") for (int j = 0; j < 4; ++j) {                   \
    aR  = MFMA(buf[j], w[0][base + j], aR, 0, 0, 0);                \
    aZ  = MFMA(buf[j], w[1][base + j], aZ, 0, 0, 0);                \
    aNH = MFMA(buf[j], w[2][base + j], aNH, 0, 0, 0);               \
  }
#define HL1_ISSUE(b0, b1, base)                                     \
  _Pragma("unroll") for (int j = 0; j < 4; ++j) {                   \
    b0[j] = ld16a(hsrc + (base + j) * 1024);                        \
    b1[j] = ld16a(hsrc + 16384 + (base + j) * 1024);                \
  }
#define HL1_MFMA(acc0, acc1, acc2, w, b0, b1, base)                 \
  _Pragma("unroll") for (int j = 0; j < 4; ++j) {                   \
    acc0[0] = MFMA(b0[j], w[0][base + j], acc0[0], 0, 0, 0);        \
    acc0[1] = MFMA(b1[j], w[0][base + j], acc0[1], 0, 0, 0);        \
    acc1[0] = MFMA(b0[j], w[1][base + j], acc1[0], 0, 0, 0);        \
    acc1[1] = MFMA(b1[j], w[1][base + j], acc1[1], 0, 0, 0);        \
    acc2[0] = MFMA(b0[j], w[2][base + j], acc2[0], 0, 0, 0);        \
    acc2[1] = MFMA(b1[j], w[2][base + j], acc2[1], 0, 0, 0);        \
  }

// ---- L0 lead (w0 rt0, w2 rt1): kc 0-7 + x; epilogue + flag0 post pre-P ----
template <bool XL>
__device__ __attribute__((noinline)) void role_l0_lead(
    const float* __restrict__ seq, const float* __restrict__ Whh0,
    const float* __restrict__ Wih0, bf16_t* __restrict__ h0b,
    unsigned* __restrict__ flg0p, unsigned* mb, unsigned* pd, float* pbuf,
    int g, int slot, int lane, int rbase, int rt, int c,
    float b0r, float b0z, float b0nx, float b0nh) {
  const int lm = lane & 15, lq = lane >> 4, koff = lq * 8;
  const int arow = rbase + rt * 16 + lm;
  const int kcb = slot >> 1;
  const int lq2 = ((slot & 1) << 1) | (lm >> 3);
  const int stoff = ((g * 2 + rt) * 16 + kcb) * 1024 +
                    ((lq2 << 4) + lq * 4) * 16 + (lm & 7) * 2;
  const int tbase = (g * 2 + rt) * 16 * 1024;
  float h0m[4] = {0.f, 0.f, 0.f, 0.f};

  if constexpr (XL) {
    bf16x8 f0[3][9];  // kc 0-7 + x
#pragma unroll
    for (int gg = 0; gg < 3; ++gg) {
      const float* wh = Whh0 + (size_t)(gg * kH + c) * kH + koff;
#pragma unroll
      for (int kc = 0; kc < 8; ++kc) f0[gg][kc] = fragf(wh + kc * 32);
      f0[gg][8] = fragf(Wih0 + (size_t)(gg * kH + c) * kF + koff);
    }
    for (int s = 0; s <= kT; ++s) {
      const int pr = (s + RING - 1) & (RING - 1), pw = s & (RING - 1);
      if (s < kT) {
        const float* xp = seq + ((size_t)arow * kT + s) * kF + koff;
        float xs[8];
#pragma unroll
        for (int j = 0; j < 8; ++j) xs[j] = xp[j];
        if (s > 0) poll_flags<XL>(flg0p, lane, (unsigned)s);
        if ((s & (RING - 1)) == 0) asm volatile("buffer_inv" ::: "memory");
        if (lane == 0) LDSVU(mb) = (unsigned)(s + 1);  // release partner
        f32x4 aR{0,0,0,0}, aZ{0,0,0,0}, aNH{0,0,0,0}, aNX{0,0,0,0};
        const char* hsrc = (const char*)h0b + pr * IMG + tbase + lane * 16;
        bf16x8 cA[4], cB[4];
        HL0_ISSUE(cA, 0);
        HL0_ISSUE(cB, 4);
        WAITVM(4);
        HL0_MFMA(f0, cA, 0);
        WAITVM(0);
        HL0_MFMA(f0, cB, 4);
        {
          bf16x8 ax;
#pragma unroll
          for (int j = 0; j < 8; ++j) ax[j] = (bf16_t)xs[j];
          aR  = MFMA(ax, f0[0][8], aR, 0, 0, 0);
          aZ  = MFMA(ax, f0[1][8], aZ, 0, 0, 0);
          aNX = MFMA(ax, f0[2][8], aNX, 0, 0, 0);
        }
        // combine partner half (kc 8-15)
        lds_poll(pd, (unsigned)(s + 1));
        float* pp = pbuf + (s & 1) * 768;
        aR  += LDSF4(pp + (0 * 64 + lane) * 4);
        aZ  += LDSF4(pp + (1 * 64 + lane) * 4);
        aNH += LDSF4(pp + (2 * 64 + lane) * 4);
        char* hnb = (char*)h0b + pw * IMG;
#pragma unroll
        for (int i = 0; i < 4; ++i) {
          float r = sigmoid_f(aR[i] + b0r);
          float z = sigmoid_f(aZ[i] + b0z);
          float n = tanh_f((aNX[i] + b0nx) + r * (aNH[i] + b0nh));
          float hn = (1.f - z) * n + z * h0m[i];
          h0m[i] = hn;
          st2x<XL>((bf16_t*)(hnb + stoff + i * 16), hn);
        }
        drain_stores();
        if (lane == 0)
          flag_post<XL>(flg0p + rt * 32 + slot, (unsigned)(s + 1));
      }
      __syncthreads();  // P
    }
  } else {
    // fallback: full-K (R20-proven body), partner idles
    bf16x8 f0[3][17];
#pragma unroll
    for (int gg = 0; gg < 3; ++gg) {
      const float* wh = Whh0 + (size_t)(gg * kH + c) * kH + koff;
#pragma unroll
      for (int kc = 0; kc < 16; ++kc) f0[gg][kc] = fragf(wh + kc * 32);
      f0[gg][16] = fragf(Wih0 + (size_t)(gg * kH + c) * kF + koff);
    }
    for (int s = 0; s <= kT; ++s) {
      const int pr = (s + RING - 1) & (RING - 1), pw = s & (RING - 1);
      if (s < kT) {
        const float* xp = seq + ((size_t)arow * kT + s) * kF + koff;
        float xs[8];
#pragma unroll
        for (int j = 0; j < 8; ++j) xs[j] = xp[j];
        if (s > 0) poll_flags<XL>(flg0p, lane, (unsigned)s);
        f32x4 aR{0,0,0,0}, aZ{0,0,0,0}, aNH{0,0,0,0}, aNX{0,0,0,0};
        const char* hsrc = (const char*)h0b + pr * IMG + tbase + lane * 16;
#pragma unroll
        for (int kc = 0; kc < 16; ++kc) {
          bf16x8 a = ld16_mall((const bf16_t*)(hsrc + kc * 1024));
          aR  = MFMA(a, f0[0][kc], aR, 0, 0, 0);
          aZ  = MFMA(a, f0[1][kc], aZ, 0, 0, 0);
          aNH = MFMA(a, f0[2][kc], aNH, 0, 0, 0);
        }
        bf16x8 ax;
#pragma unroll
        for (int j = 0; j < 8; ++j) ax[j] = (bf16_t)xs[j];
        aR  = MFMA(ax, f0[0][16], aR, 0, 0, 0);
        aZ  = MFMA(ax, f0[1][16], aZ, 0, 0, 0);
        aNX = MFMA(ax, f0[2][16], aNX, 0, 0, 0);
        char* hnb = (char*)h0b + pw * IMG;
#pragma unroll
        for (int i = 0; i < 4; ++i) {
          float r = sigmoid_f(aR[i] + b0r);
          float z = sigmoid_f(aZ[i] + b0z);
          float n = tanh_f((aNX[i] + b0nx) + r * (aNH[i] + b0nh));
          float hn = (1.f - z) * n + z * h0m[i];
          h0m[i] = hn;
          st2x<XL>((bf16_t*)(hnb + stoff + i * 16), hn);
        }
        drain_stores();
        if (lane == 0)
          flag_post<XL>(flg0p + rt * 32 + slot, (unsigned)(s + 1));
      }
      __syncthreads();  // P
      __syncthreads();  // B
    }
  }
}

// ---- L0 partner (w4 rt0, w6 rt1): kc 8-15 -> LDS partial + pd ----
template <bool XL>
__device__ __attribute__((noinline)) void role_l0_part(
    const float* __restrict__ Whh0, bf16_t* __restrict__ h0b,
    unsigned* mb, unsigned* pd, float* pbuf,
    int g, int lane, int rt, int c) {
  if constexpr (XL) {
    const int lq = lane >> 4, koff = lq * 8;
    bf16x8 f4[3][8];  // kc 8-15
#pragma unroll
    for (int gg = 0; gg < 3; ++gg) {
      const float* wh = Whh0 + (size_t)(gg * kH + c) * kH + koff;
#pragma unroll
      for (int kc = 0; kc < 8; ++kc) f4[gg][kc] = fragf(wh + (8 + kc) * 32);
    }
    const int tbase = (g * 2 + rt) * 16 * 1024;
    for (int s = 0; s <= kT; ++s) {
      const int pr = (s + RING - 1) & (RING - 1);
      if (s < kT) {
        lds_poll(mb, (unsigned)(s + 1));  // lead passed its gate
        if ((s & (RING - 1)) == 0) asm volatile("buffer_inv" ::: "memory");
        f32x4 aR{0,0,0,0}, aZ{0,0,0,0}, aNH{0,0,0,0};
        const char* hsrc =
            (const char*)h0b + pr * IMG + tbase + 8192 + lane * 16;
        bf16x8 cA[4], cB[4];
        HL0_ISSUE(cA, 0);
        HL0_ISSUE(cB, 4);
        WAITVM(4);
        HL0_MFMA(f4, cA, 0);
        WAITVM(0);
        HL0_MFMA(f4, cB, 4);
        float* pp = pbuf + (s & 1) * 768;
        LDSF4(pp + (0 * 64 + lane) * 4) = aR;
        LDSF4(pp + (1 * 64 + lane) * 4) = aZ;
        LDSF4(pp + (2 * 64 + lane) * 4) = aNH;
        asm volatile("s_waitcnt lgkmcnt(0)" ::: "memory");
        if (lane == 0) LDSVU(pd) = (unsigned)(s + 1);
      }
      __syncthreads();  // P
    }
  } else {
    for (int s = 0; s <= kT; ++s) { __syncthreads(); __syncthreads(); }
  }
}

// ---- L1h lead (w1): kc 0-7 h1; combine + epilogue + flag1 post ----
template <bool XL>
__device__ __attribute__((noinline)) void role_l1h_lead(
    const float* __restrict__ Whh1, bf16_t* __restrict__ h1b,
    float* __restrict__ h1f, unsigned* __restrict__ flg1p, int slot,
    float* p1b, float* p3b, unsigned* mb, int g, int lane, int rbase, int c,
    float b1r, float b1z, float b1nx, float b1nh) {
  const int lm = lane & 15, lq = lane >> 4, koff = lq * 8;
  const int kcb = slot >> 1;
  const int lq2 = ((slot & 1) << 1) | (lm >> 3);
  const int st0 = (g * 2 * 16 + kcb) * 1024 +
                  ((lq2 << 4) + lq * 4) * 16 + (lm & 7) * 2;
  const int tbase = g * 2 * 16 * 1024;
  float h1m[2][4] = {{0,0,0,0},{0,0,0,0}};

  if constexpr (XL) {
    bf16x8 fh[3][8];
#pragma unroll
    for (int gg = 0; gg < 3; ++gg) {
      const float* wh = Whh1 + (size_t)(gg * kH + c) * kH + koff;
#pragma unroll
      for (int kc = 0; kc < 8; ++kc) fh[gg][kc] = fragf(wh + kc * 32);
    }
    for (int s = 0; s <= kT; ++s) {
      const int pr = (s + RING - 1) & (RING - 1), pw = s & (RING - 1);
      f32x4 cR[2], cZ[2], cNH[2];
#pragma unroll
      for (int rt = 0; rt < 2; ++rt) {
        cR[rt] = f32x4{0,0,0,0}; cZ[rt] = f32x4{0,0,0,0};
        cNH[rt] = f32x4{0,0,0,0};
      }
      if (s >= 1) {
        poll_flags<XL>(flg1p, lane & 31, (unsigned)s);
        if ((s & (RING - 1)) == 0) asm volatile("buffer_inv" ::: "memory");
        if (lane == 0) LDSVU(mb) = (unsigned)(s + 1);
        const char* hsrc = (const char*)h1b + pr * IMG + tbase + lane * 16;
        bf16x8 a0A[4], a1A[4], a0B[4], a1B[4];
        HL1_ISSUE(a0A, a1A, 0);
        HL1_ISSUE(a0B, a1B, 4);
        WAITVM(8);
        HL1_MFMA(cR, cZ, cNH, fh, a0A, a1A, 0);
        WAITVM(0);
        HL1_MFMA(cR, cZ, cNH, fh, a0B, a1B, 4);
      }
      __syncthreads();  // P: all partials visible
      if (s >= 1) {
        float* p5 = p1b + (s & 1) * 1536;
        float* pa = p3b + (s & 1) * 3072;
        float* pb = pa + 1536;
        char* hnb = (char*)h1b + pw * IMG;
#pragma unroll
        for (int rt = 0; rt < 2; ++rt) {
          f32x4 cr = cR[rt]  + LDSF4(p5 + ((rt * 3 + 0) * 64 + lane) * 4);
          f32x4 cz = cZ[rt]  + LDSF4(p5 + ((rt * 3 + 1) * 64 + lane) * 4);
          f32x4 cn = cNH[rt] + LDSF4(p5 + ((rt * 3 + 2) * 64 + lane) * 4);
          f32x4 pR  = LDSF4(pa + ((rt * 3 + 0) * 64 + lane) * 4) +
                      LDSF4(pb + ((rt * 3 + 0) * 64 + lane) * 4);
          f32x4 pZ  = LDSF4(pa + ((rt * 3 + 1) * 64 + lane) * 4) +
                      LDSF4(pb + ((rt * 3 + 1) * 64 + lane) * 4);
          f32x4 pNX = LDSF4(pa + ((rt * 3 + 2) * 64 + lane) * 4) +
                      LDSF4(pb + ((rt * 3 + 2) * 64 + lane) * 4);
#pragma unroll
          for (int i = 0; i < 4; ++i) {
            float r = sigmoid_f(cr[i] + pR[i] + b1r);
            float z = sigmoid_f(cz[i] + pZ[i] + b1z);
            float n = tanh_f((pNX[i] + b1nx) + r * (cn[i] + b1nh));
            float hn = (1.f - z) * n + z * h1m[rt][i];
            h1m[rt][i] = hn;
            if (s < kT)
              st2x<XL>((bf16_t*)(hnb + st0 + rt * 16384 + i * 16), hn);
            else
              h1f[(rbase + rt * 16 + lq * 4 + i) * kH + c] = hn;
          }
        }
      }
      if (s < kT) {
        drain_stores();
        if (lane == 0) flag_post<XL>(flg1p + slot, (unsigned)(s + 1));
      }
    }
  } else {
    // fallback: full-K (R20 body); w3's fallback partial in p3b writer 0
    bf16x8 fh[3][16];
#pragma unroll
    for (int gg = 0; gg < 3; ++gg) {
      const float* wh = Whh1 + (size_t)(gg * kH + c) * kH + koff;
#pragma unroll
      for (int kc = 0; kc < 16; ++kc) fh[gg][kc] = fragf(wh + kc * 32);
    }
    for (int s = 0; s <= kT; ++s) {
      const int pr = (s + RING - 1) & (RING - 1), pw = s & (RING - 1);
      f32x4 cR[2], cZ[2], cNH[2];
#pragma unroll
      for (int rt = 0; rt < 2; ++rt) {
        cR[rt] = f32x4{0,0,0,0}; cZ[rt] = f32x4{0,0,0,0};
        cNH[rt] = f32x4{0,0,0,0};
      }
      if (s >= 1) {
        poll_flags<XL>(flg1p, lane & 31, (unsigned)s);
        const char* hsrc = (const char*)h1b + pr * IMG + tbase + lane * 16;
#pragma unroll
        for (int kc = 0; kc < 16; ++kc) {
          bf16x8 a0 = ld16_mall((const bf16_t*)(hsrc + kc * 1024));
          bf16x8 a1 = ld16_mall((const bf16_t*)(hsrc + 16384 + kc * 1024));
          cR[0]  = MFMA(a0, fh[0][kc], cR[0], 0,0,0);
          cR[1]  = MFMA(a1, fh[0][kc], cR[1], 0,0,0);
          cZ[0]  = MFMA(a0, fh[1][kc], cZ[0], 0,0,0);
          cZ[1]  = MFMA(a1, fh[1][kc], cZ[1], 0,0,0);
          cNH[0] = MFMA(a0, fh[2][kc], cNH[0],0,0,0);
          cNH[1] = MFMA(a1, fh[2][kc], cNH[1],0,0,0);
        }
      }
      __syncthreads();  // P
      if (s >= 1) {
        float* pa = p3b + (s & 1) * 3072;  // w3 fallback full-K partial
        char* hnb = (char*)h1b + pw * IMG;
#pragma unroll
        for (int rt = 0; rt < 2; ++rt) {
          f32x4 pR  = LDSF4(pa + ((rt * 3 + 0) * 64 + lane) * 4);
          f32x4 pZ  = LDSF4(pa + ((rt * 3 + 1) * 64 + lane) * 4);
          f32x4 pNX = LDSF4(pa + ((rt * 3 + 2) * 64 + lane) * 4);
#pragma unroll
          for (int i = 0; i < 4; ++i) {
            float r = sigmoid_f(cR[rt][i] + pR[i] + b1r);
            float z = sigmoid_f(cZ[rt][i] + pZ[i] + b1z);
            float n = tanh_f((pNX[i] + b1nx) + r * (cNH[rt][i] + b1nh));
            float hn = (1.f - z) * n + z * h1m[rt][i];
            h1m[rt][i] = hn;
            if (s < kT)
              st2x<XL>((bf16_t*)(hnb + st0 + rt * 16384 + i * 16), hn);
            else
              h1f[(rbase + rt * 16 + lq * 4 + i) * kH + c] = hn;
          }
        }
      }
      if (s < kT) {
        drain_stores();
        if (lane == 0) flag_post<XL>(flg1p + slot, (unsigned)(s + 1));
        poll_flags<XL>(flg1p, lane & 31, (unsigned)(s + 1));
      }
      __syncthreads();  // B
    }
  }
}

// ---- L1h partner (w5): kc 8-15 h1 -> LDS partial ----
template <bool XL>
__device__ __attribute__((noinline)) void role_l1h_part(
    const float* __restrict__ Whh1, bf16_t* __restrict__ h1b,
    float* p1b, unsigned* mb, int g, int lane, int c) {
  if constexpr (XL) {
    const int lq = lane >> 4, koff = lq * 8;
    bf16x8 fh[3][8];
#pragma unroll
    for (int gg = 0; gg < 3; ++gg) {
      const float* wh = Whh1 + (size_t)(gg * kH + c) * kH + koff;
#pragma unroll
      for (int kc = 0; kc < 8; ++kc) fh[gg][kc] = fragf(wh + (8 + kc) * 32);
    }
    const int tbase = g * 2 * 16 * 1024;
    for (int s = 0; s <= kT; ++s) {
      const int pr = (s + RING - 1) & (RING - 1);
      if (s >= 1) {
        lds_poll(mb, (unsigned)(s + 1));
        if ((s & (RING - 1)) == 0) asm volatile("buffer_inv" ::: "memory");
        f32x4 cR[2], cZ[2], cNH[2];
#pragma unroll
        for (int rt = 0; rt < 2; ++rt) {
          cR[rt] = f32x4{0,0,0,0}; cZ[rt] = f32x4{0,0,0,0};
          cNH[rt] = f32x4{0,0,0,0};
        }
        const char* hsrc =
            (const char*)h1b + pr * IMG + tbase + 8192 + lane * 16;
        bf16x8 a0A[4], a1A[4], a0B[4], a1B[4];
        HL1_ISSUE(a0A, a1A, 0);
        HL1_ISSUE(a0B, a1B, 4);
        WAITVM(8);
        HL1_MFMA(cR, cZ, cNH, fh, a0A, a1A, 0);
        WAITVM(0);
        HL1_MFMA(cR, cZ, cNH, fh, a0B, a1B, 4);
        float* pp = p1b + (s & 1) * 1536;
#pragma unroll
        for (int rt = 0; rt < 2; ++rt) {
          LDSF4(pp + ((rt * 3 + 0) * 64 + lane) * 4) = cR[rt];
          LDSF4(pp + ((rt * 3 + 1) * 64 + lane) * 4) = cZ[rt];
          LDSF4(pp + ((rt * 3 + 2) * 64 + lane) * 4) = cNH[rt];
        }
      }
      __syncthreads();  // P
    }
  } else {
    for (int s = 0; s <= kT; ++s) { __syncthreads(); __syncthreads(); }
  }
}

// ---- L1x (w3 lead kc0-7 / w7 partner kc8-15): h0 x-part -> LDS ----
template <bool XL, bool LEAD>
__device__ __attribute__((noinline)) void role_l1x_w(
    const float* __restrict__ Wih1, bf16_t* __restrict__ h0b,
    float* p3b, unsigned* __restrict__ flg0p, unsigned* mb,
    int g, int lane, int c) {
  const int lq = lane >> 4, koff = lq * 8;
  const int tbase = g * 2 * 16 * 1024;
  if constexpr (XL) {
    bf16x8 fx[3][8];
#pragma unroll
    for (int gg = 0; gg < 3; ++gg) {
      const float* wi = Wih1 + (size_t)(gg * kH + c) * kH + koff;
#pragma unroll
      for (int kc = 0; kc < 8; ++kc)
        fx[gg][kc] = fragf(wi + (LEAD ? kc : 8 + kc) * 32);
    }
    for (int s = 0; s <= kT; ++s) {
      const int pr = (s + RING - 1) & (RING - 1);
      if (s >= 1) {
        if constexpr (LEAD) {
          poll_flags<XL>(flg0p, lane, (unsigned)s);
          if ((s & (RING - 1)) == 0) asm volatile("buffer_inv" ::: "memory");
          if (lane == 0) LDSVU(mb) = (unsigned)(s + 1);
        } else {
          lds_poll(mb, (unsigned)(s + 1));
          if ((s & (RING - 1)) == 0) asm volatile("buffer_inv" ::: "memory");
        }
        f32x4 xR[2], xZ[2], xNX[2];
#pragma unroll
        for (int rt = 0; rt < 2; ++rt) {
          xR[rt] = f32x4{0,0,0,0}; xZ[rt] = f32x4{0,0,0,0};
          xNX[rt] = f32x4{0,0,0,0};
        }
        const char* hsrc = (const char*)h0b + pr * IMG + tbase +
                           (LEAD ? 0 : 8192) + lane * 16;
        bf16x8 a0A[4], a1A[4], a0B[4], a1B[4];
        HL1_ISSUE(a0A, a1A, 0);
        HL1_ISSUE(a0B, a1B, 4);
        WAITVM(8);
        HL1_MFMA(xR, xZ, xNX, fx, a0A, a1A, 0);
        WAITVM(0);
        HL1_MFMA(xR, xZ, xNX, fx, a0B, a1B, 4);
        float* pp = p3b + (s & 1) * 3072 + (LEAD ? 0 : 1536);
#pragma unroll
        for (int rt = 0; rt < 2; ++rt) {
          LDSF4(pp + ((rt * 3 + 0) * 64 + lane) * 4) = xR[rt];
          LDSF4(pp + ((rt * 3 + 1) * 64 + lane) * 4) = xZ[rt];
          LDSF4(pp + ((rt * 3 + 2) * 64 + lane) * 4) = xNX[rt];
        }
      }
      __syncthreads();  // P
    }
  } else {
    if constexpr (LEAD) {
      bf16x8 fx[3][16];
#pragma unroll
      for (int gg = 0; gg < 3; ++gg) {
        const float* wi = Wih1 + (size_t)(gg * kH + c) * kH + koff;
#pragma unroll
        for (int kc = 0; kc < 16; ++kc) fx[gg][kc] = fragf(wi + kc * 32);
      }
      for (int s = 0; s <= kT; ++s) {
        const int pr = (s + RING - 1) & (RING - 1);
        if (s >= 1) {
          poll_flags<XL>(flg0p, lane, (unsigned)s);
          f32x4 xR[2], xZ[2], xNX[2];
#pragma unroll
          for (int rt = 0; rt < 2; ++rt) {
            xR[rt] = f32x4{0,0,0,0}; xZ[rt] = f32x4{0,0,0,0};
            xNX[rt] = f32x4{0,0,0,0};
          }
          const char* hsrc = (const char*)h0b + pr * IMG + tbase + lane * 16;
#pragma unroll
          for (int kc = 0; kc < 16; ++kc) {
            bf16x8 a0 = ld16_mall((const bf16_t*)(hsrc + kc * 1024));
            bf16x8 a1 = ld16_mall((const bf16_t*)(hsrc + 16384 + kc * 1024));
            xR[0]  = MFMA(a0, fx[0][kc], xR[0], 0,0,0);
            xR[1]  = MFMA(a1, fx[0][kc], xR[1], 0,0,0);
            xZ[0]  = MFMA(a0, fx[1][kc], xZ[0], 0,0,0);
            xZ[1]  = MFMA(a1, fx[1][kc], xZ[1], 0,0,0);
            xNX[0] = MFMA(a0, fx[2][kc], xNX[0],0,0,0);
            xNX[1] = MFMA(a1, fx[2][kc], xNX[1],0,0,0);
          }
          float* pp = p3b + (s & 1) * 3072;
#pragma unroll
          for (int rt = 0; rt < 2; ++rt) {
            LDSF4(pp + ((rt * 3 + 0) * 64 + lane) * 4) = xR[rt];
            LDSF4(pp + ((rt * 3 + 1) * 64 + lane) * 4) = xZ[rt];
            LDSF4(pp + ((rt * 3 + 2) * 64 + lane) * 4) = xNX[rt];
          }
        }
        __syncthreads();  // P
        __syncthreads();  // B
      }
    } else {
      for (int s = 0; s <= kT; ++s) { __syncthreads(); __syncthreads(); }
    }
  }
}

__launch_bounds__(NTHR, 1)
__global__ void gru_persistent(
    const float* __restrict__ seq,
    const float* __restrict__ Wih0, const float* __restrict__ Whh0,
    const float* __restrict__ bih0, const float* __restrict__ bhh0,
    const float* __restrict__ Wih1, const float* __restrict__ Whh1,
    const float* __restrict__ bih1, const float* __restrict__ bhh1,
    char* __restrict__ ws) {
  extern __shared__ char smem[];
  float* pb0 = (float*)(smem + PB0_OFF);
  float* pb2 = (float*)(smem + PB2_OFF);
  float* pb1 = (float*)(smem + PB1_OFF);
  float* pb3 = (float*)(smem + PB3_OFF);
  unsigned* mb0 = (unsigned*)(smem + HS_OFF + 0);
  unsigned* pd0 = (unsigned*)(smem + HS_OFF + 128);
  unsigned* mb2 = (unsigned*)(smem + HS_OFF + 256);
  unsigned* pd2 = (unsigned*)(smem + HS_OFF + 384);
  unsigned* mb1 = (unsigned*)(smem + HS_OFF + 512);
  unsigned* mb3 = (unsigned*)(smem + HS_OFF + 640);
  __shared__ unsigned sh_enc;

  const int tid = threadIdx.x;

  // ---- self-organization: group = physical XCD, slot = per-XCD ordinal ----
  if (tid == 0) {
    LDSVU(mb0) = 0u; LDSVU(pd0) = 0u; LDSVU(mb2) = 0u;
    LDSVU(pd2) = 0u; LDSVU(mb1) = 0u; LDSVU(mb3) = 0u;
    unsigned xcd;
    asm("s_getreg_b32 %0, hwreg(HW_REG_XCC_ID)" : "=s"(xcd));
    xcd &= 7;
    unsigned* cnt   = (unsigned*)(ws + WS_CNT) + xcd * 32;
    unsigned* total = (unsigned*)(ws + WS_TOTAL);
    unsigned* fb    = (unsigned*)(ws + WS_FB);
    unsigned slot = __hip_atomic_fetch_add(cnt, 1u, __ATOMIC_RELAXED,
                                           __HIP_MEMORY_SCOPE_AGENT);
    if (slot >= 32)
      __hip_atomic_store(fb, 1u, __ATOMIC_RELAXED, __HIP_MEMORY_SCOPE_AGENT);
    __hip_atomic_fetch_add(total, 1u, __ATOMIC_RELAXED,
                           __HIP_MEMORY_SCOPE_AGENT);
    long guard = 0;
    while (__hip_atomic_load(total, __ATOMIC_RELAXED,
                             __HIP_MEMORY_SCOPE_AGENT) < (unsigned)GBLK) {
      __builtin_amdgcn_s_sleep(1);  // one-time startup
      if (++guard > (1L << 24)) break;
    }
    unsigned f = __hip_atomic_load(fb, __ATOMIC_RELAXED,
                                   __HIP_MEMORY_SCOPE_AGENT);
    sh_enc = (f << 31) | (xcd << 8) | (slot & 255);
  }
  __syncthreads();
  const unsigned enc = sh_enc;
  const bool fallback = (enc >> 31) != 0;
  const int g    = fallback ? (blockIdx.x & 7)  : (int)((enc >> 8) & 7);
  const int slot = fallback ? (blockIdx.x >> 3) : (int)(enc & 255);
  const int hs   = slot * HB;

  const int lm = tid & 15;
  const int c = hs + lm;
  const float b0r  = bih0[c] + bhh0[c];
  const float b0z  = bih0[kH + c] + bhh0[kH + c];
  const float b0nx = bih0[2 * kH + c];
  const float b0nh = bhh0[2 * kH + c];
  const float b1r  = bih1[c] + bhh1[c];
  const float b1z  = bih1[kH + c] + bhh1[kH + c];
  const float b1nx = bih1[2 * kH + c];
  const float b1nh = bhh1[2 * kH + c];

  bf16_t* h0b = (bf16_t*)(ws + WS_H0B);
  bf16_t* h1b = (bf16_t*)(ws + WS_H1B);
  float*  h1f = (float*)(ws + WS_H1F);
  unsigned* flg1p = (unsigned*)(ws + WS_FLG1) + g * 32;  // 128B/group
  unsigned* flg0p = (unsigned*)(ws + WS_FLG0) + g * 64;  // 256B/group
  const int wv   = tid >> 6;     // 0..7
  const int lane = tid & 63;
  const int rbase = g * RG;

#define DISPATCH(XLV)                                                       \
  do {                                                                      \
    if (wv == 0)                                                            \
      role_l0_lead<XLV>(seq, Whh0, Wih0, h0b, flg0p, mb0, pd0, pb0, g,      \
                        slot, lane, rbase, 0, c, b0r, b0z, b0nx, b0nh);     \
    else if (wv == 4)                                                       \
      role_l0_part<XLV>(Whh0, h0b, mb0, pd0, pb0, g, lane, 0, c);           \
    else if (wv == 2)                                                       \
      role_l0_lead<XLV>(seq, Whh0, Wih0, h0b, flg0p, mb2, pd2, pb2, g,      \
                        slot, lane, rbase, 1, c, b0r, b0z, b0nx, b0nh);     \
    else if (wv == 6)                                                       \
      role_l0_part<XLV>(Whh0, h0b, mb2, pd2, pb2, g, lane, 1, c);           \
    else if (wv == 1)                                                       \
      role_l1h_lead<XLV>(Whh1, h1b, h1f, flg1p, slot, pb1, pb3, mb1, g,     \
                         lane, rbase, c, b1r, b1z, b1nx, b1nh);             \
    else if (wv == 5)                                                       \
      role_l1h_part<XLV>(Whh1, h1b, pb1, mb1, g, lane, c);                  \
    else if (wv == 3)                                                       \
      role_l1x_w<XLV, true>(Wih1, h0b, pb3, flg0p, mb3, g, lane, c);        \
    else                                                                    \
      role_l1x_w<XLV, false>(Wih1, h0b, pb3, flg0p, mb3, g, lane, c);       \
  } while (0)

  if (!fallback) DISPATCH(true);
  else           DISPATCH(false);
#undef DISPATCH
}

// ---- head: concat(h1_last, embed) -> fc1+relu -> fc2 ----
__global__ void head_kernel(const float* __restrict__ h1,
                            const int* __restrict__ ticker,
                            const float* __restrict__ etab,
                            const float* __restrict__ fc1w,
                            const float* __restrict__ fc1b,
                            const float* __restrict__ fc2w,
                            const float* __restrict__ fc2b,
                            float* __restrict__ out) {
  __shared__ float xin[4][kH + kE];
  __shared__ float y1[4][kH];
  const int tid = threadIdx.x;
  const int b0 = blockIdx.x * 4;

  for (int idx = tid; idx < 4 * (kH + kE); idx += 256) {
    const int r = idx / (kH + kE), k = idx % (kH + kE);
    const int b = b0 + r;
    xin[r][k] = (k < kH) ? h1[b * kH + k] : etab[ticker[b] * kE + (k - kH)];
  }
  __syncthreads();

#pragma unroll
  for (int jj = 0; jj < 2; ++jj) {
    const int j = tid + jj * 256;
    const float* wr = fc1w + j * (kH + kE);
    float a0 = 0.f, a1 = 0.f, a2 = 0.f, a3 = 0.f;
    for (int k = 0; k < kH + kE; ++k) {
      const float w = wr[k];
      a0 += w * xin[0][k];
      a1 += w * xin[1][k];
      a2 += w * xin[2][k];
      a3 += w * xin[3][k];
    }
    const float bb = fc1b[j];
    y1[0][j] = fmaxf(a0 + bb, 0.f);
    y1[1][j] = fmaxf(a1 + bb, 0.f);
    y1[2][j] = fmaxf(a2 + bb, 0.f);
    y1[3][j] = fmaxf(a3 + bb, 0.f);
  }
  __syncthreads();

  if (tid < 4 * kPD) {
    const int r = tid / kPD, j = tid % kPD;
    const float* wr = fc2w + j * kH;
    float acc = fc2b[j];
    for (int k = 0; k < kH; ++k) acc += wr[k] * y1[r][k];
    out[(b0 + r) * kPD + j] = acc;
  }
}

extern "C" void kernel_launch(void* const* d_in, const int* in_sizes, int n_in,
                              void* d_out, int out_size, void* d_ws,
                              size_t ws_size, hipStream_t stream) {
  (void)in_sizes; (void)n_in; (void)out_size; (void)ws_size;

  const int*   ticker = (const int*)d_in[0];
  const float* seq    = (const float*)d_in[1];
  const float* etab   = (const float*)d_in[2];
  const float* Wih0   = (const float*)d_in[3];
  const float* Whh0   = (const float*)d_in[4];
  const float* bih0   = (const float*)d_in[5];
  const float* bhh0   = (const float*)d_in[6];
  const float* Wih1   = (const float*)d_in[7];
  const float* Whh1   = (const float*)d_in[8];
  const float* bih1   = (const float*)d_in[9];
  const float* bhh1   = (const float*)d_in[10];
  const float* fc1w   = (const float*)d_in[11];
  const float* fc1b   = (const float*)d_in[12];
  const float* fc2w   = (const float*)d_in[13];
  const float* fc2b   = (const float*)d_in[14];

  char* ws = (char*)d_ws;
  (void)hipMemsetAsync(ws, 0, WS_INIT, stream);  // counters+flags+both rings

  gru_persistent<<<GBLK, NTHR, LDSB, stream>>>(
      seq, Wih0, Whh0, bih0, bhh0, Wih1, Whh1, bih1, bhh1, ws);

  head_kernel<<<kB / 4, 256, 0, stream>>>((const float*)(ws + WS_H1F), ticker,
                                          etab, fc1w, fc1b, fc2w, fc2b,
                                          (float*)d_out);
}

// Round 16
// 2176.255 us; speedup vs baseline: 1.2065x; 1.2065x over previous
//
#include <hip/hip_runtime.h>
#include <hip/hip_bf16.h>

// ---------------------------------------------------------------------------
// Persistent fused 2-layer GRU + head for MI355X (gfx950).
//
// R24 -> R25 (FINAL): revert to R20 byte-for-byte -- the session optimum.
// Ledger (steady us): R9 3272 -> R15 2961 (w1-only sc1 polls, 1 inv/step)
// -> R18 2502 (2-deep vmcnt pipelines) -> R20 2135 (split-flag DAG, L2
// polls). Attempts past R20 all regressed: wave decoupling (R21 4045 /
// R22 4172: per-wave poll traffic + lost batching), 3-deep pipes + sc1
// posts (R23 2345), 8-wave TLP pair-split (R24 2540: LDS pair handshake
// on the lead's critical path outweighs latency hiding). The kernel is
// latency-bound on the inherent 512-step cross-CU recurrence (not HBM /
// not MFMA bound); R20's step = poll(sc1, L2) + 2-deep pipelined compute
// + single P + early split flags is the measured floor of this dataflow.
//  * Structure: 8 XCD groups x 32 CUs; frag-major 8-ring h images; flag0
//    posted by w0/w2 pre-P (gates w0/w2/w3), flag1 by w1 post-epilogue
//    (gates w1); sc1 read-only polls; plain write-through posts; one
//    buffer_inv per wave per 8 steps; part double-buffered by s&1.
// ---------------------------------------------------------------------------

namespace {
constexpr int kB  = 256;   // batch
constexpr int kT  = 512;   // time steps
constexpr int kF  = 32;    // input features
constexpr int kH  = 512;   // hidden
constexpr int kE  = 32;    // embed dim
constexpr int kPD = 30;    // predict days

constexpr int GBLK = 256;  // 8 XCD groups x 32 hidden slots, 1 block/CU
constexpr int NTHR = 256;  // 4 waves
constexpr int RG   = 32;   // batch rows per group
constexpr int HB   = 16;   // hidden cols per block

constexpr int IMG  = kB * kH * 2;  // 256 KiB per h image (one step)
constexpr int RING = 8;            // ring depth (address reuse period)

// LDS: 2x fp32 partial-handoff buffers; alloc large to pin 1 block/CU.
constexpr int PART_OFF = 0;        // 2 x 6 KiB partials (double-buffered)
constexpr int PARTN    = 1536;     // floats per buffer
constexpr int LDSB     = 98304;
static_assert(LDSB <= 160 * 1024, "LDS overflow");

// ws layout (bytes)
constexpr size_t WS_CNT   = 0;        // 8 per-XCD counters, 128B apart
constexpr size_t WS_TOTAL = 1024;     // arrival counter
constexpr size_t WS_FB    = 1152;     // fallback flag
constexpr size_t WS_FLG1  = 2048;     // 8 groups x 32 u32 (128B stride)
constexpr size_t WS_FLG0  = 4096;     // 8 groups x 64 u32 (256B stride)
constexpr size_t WS_H0B   = 65536;                          // RING*IMG
constexpr size_t WS_H1B   = WS_H0B + (size_t)RING * IMG;    // RING*IMG
constexpr size_t WS_H1F   = WS_H1B + (size_t)RING * IMG;    // B*H f32
constexpr size_t WS_INIT  = WS_H1F;   // zero [0, WS_H1F)

typedef __bf16 bf16_t;
typedef __bf16 bf16x8 __attribute__((ext_vector_type(8)));
typedef float  f32x4  __attribute__((ext_vector_type(4)));

#define MFMA __builtin_amdgcn_mfma_f32_16x16x32_bf16
#define LDSF4(p) (*(__attribute__((address_space(3))) f32x4*)(p))

// counted vmcnt wait + scheduler fence (rule #18)
#define WAITVM(N)                                              \
  do {                                                         \
    asm volatile("s_waitcnt vmcnt(" #N ")" ::: "memory");      \
    __builtin_amdgcn_sched_barrier(0);                         \
  } while (0)

__device__ __forceinline__ float sigmoid_f(float x) {
  return 1.f / (1.f + __expf(-x));
}
__device__ __forceinline__ float tanh_f(float x) {
  float a = fabsf(x);
  float e = __expf(-2.f * a);
  float t = (1.f - e) / (1.f + e);
  return copysignf(t, x);
}

// Plain (L1-allocating) 16B load, NOT waited (caller manages vmcnt).
__device__ __forceinline__ bf16x8 ld16a(const char* p) {
  bf16x8 v;
  asm volatile("global_load_dwordx4 %0, %1, off"
               : "=v"(v) : "v"(p) : "memory");
  return v;
}

// 8 consecutive f32 -> bf16x8 fragment
__device__ __forceinline__ bf16x8 fragf(const float* p) {
  bf16x8 t;
#pragma unroll
  for (int j = 0; j < 8; ++j) t[j] = (bf16_t)p[j];
  return t;
}

// MALL-coherent primitives (fallback path only)
__device__ __forceinline__ bf16x8 ld16_mall(const bf16_t* p) {
  const unsigned long long* q = (const unsigned long long*)p;
  unsigned long long lo =
      __hip_atomic_load(q, __ATOMIC_RELAXED, __HIP_MEMORY_SCOPE_AGENT);
  unsigned long long hi =
      __hip_atomic_load(q + 1, __ATOMIC_RELAXED, __HIP_MEMORY_SCOPE_AGENT);
  union { unsigned long long u[2]; bf16x8 v; } x;
  x.u[0] = lo; x.u[1] = hi;
  return x.v;
}

__device__ __forceinline__ void st2_mall(bf16_t* p, float v) {
  bf16_t b = (bf16_t)v;
  unsigned short bits = __builtin_bit_cast(unsigned short, b);
  __hip_atomic_store((unsigned short*)p, bits, __ATOMIC_RELAXED,
                     __HIP_MEMORY_SCOPE_AGENT);
}
template <bool XL>
__device__ __forceinline__ void st2x(bf16_t* p, float v) {
  if constexpr (XL) *p = (bf16_t)v;
  else st2_mall(p, v);
}

__device__ __forceinline__ void drain_stores() {
  asm volatile("s_waitcnt vmcnt(0)" ::: "memory");
}

// Device-scope (sc1) 4B READ-ONLY flag load (R20-proven).
__device__ __forceinline__ unsigned ld_flag_sc1(const unsigned* p) {
  unsigned v;
  asm volatile("global_load_dword %0, %1, off sc1\n\ts_waitcnt vmcnt(0)"
               : "=v"(v) : "v"(p) : "memory");
  return v;
}

// Poll `base[idx]` until all participating lanes see >= tgt.
template <bool XL>
__device__ __forceinline__ void poll_flags(const unsigned* base, int idx,
                                           unsigned tgt) {
  const unsigned* fp = base + idx;
  long guard = 0;
  if constexpr (XL) {
    for (;;) {
      unsigned v = ld_flag_sc1(fp);
      if (__all((int)(v >= tgt))) break;
      if (++guard > (1L << 22)) break;  // co-residency guaranteed
    }
  } else {
    for (;;) {
      unsigned v = __hip_atomic_load(fp, __ATOMIC_RELAXED,
                                     __HIP_MEMORY_SCOPE_AGENT);
      if (__all((int)(v >= tgt))) break;
      __builtin_amdgcn_s_sleep(1);  // emergency path only
      if (++guard > (1L << 20)) break;
    }
  }
}

template <bool XL>
__device__ __forceinline__ void flag_post(unsigned* p, unsigned tgt) {
  if constexpr (XL) {
    *(volatile unsigned*)p = tgt;  // write-through to L2 (after drain)
  } else {
    __hip_atomic_store(p, tgt, __ATOMIC_RELAXED, __HIP_MEMORY_SCOPE_AGENT);
  }
}
}  // namespace

// Fragment-major image layout: byte off = ((g*2+rt)*16 + kc)*1024 + lane*16
// Ring: image for step s lives at slot (s & 7) * IMG.

// pipeline macros (shared by the three roles)
#define L0_ISSUE(buf, base)                                         \
  _Pragma("unroll") for (int j = 0; j < 4; ++j)                     \
      buf[j] = ld16a(hsrc + (base + j) * 1024)
#define L0_MFMA(buf, base)                                          \
  _Pragma("unroll") for (int j = 0; j < 4; ++j) {                   \
    aR  = MFMA(buf[j], f0[0][base + j], aR, 0, 0, 0);               \
    aZ  = MFMA(buf[j], f0[1][base + j], aZ, 0, 0, 0);               \
    aNH = MFMA(buf[j], f0[2][base + j], aNH, 0, 0, 0);              \
  }
#define L1_ISSUE(b0, b1, base)                                      \
  _Pragma("unroll") for (int j = 0; j < 4; ++j) {                   \
    b0[j] = ld16a(hsrc + (base + j) * 1024);                        \
    b1[j] = ld16a(hsrc + 16384 + (base + j) * 1024);                \
  }
#define L1_MFMA(acc0, acc1, acc2, w, b0, b1, base)                  \
  _Pragma("unroll") for (int j = 0; j < 4; ++j) {                   \
    acc0[0] = MFMA(b0[j], w[0][base + j], acc0[0], 0, 0, 0);        \
    acc0[1] = MFMA(b1[j], w[0][base + j], acc0[1], 0, 0, 0);        \
    acc1[0] = MFMA(b0[j], w[1][base + j], acc1[0], 0, 0, 0);        \
    acc1[1] = MFMA(b1[j], w[1][base + j], acc1[1], 0, 0, 0);        \
    acc2[0] = MFMA(b0[j], w[2][base + j], acc2[0], 0, 0, 0);        \
    acc2[1] = MFMA(b1[j], w[2][base + j], acc2[1], 0, 0, 0);        \
  }

// ---- role: layer 0, one row tile (waves 0 and 2) ----
template <bool XL>
__device__ __attribute__((noinline)) void role_l0(
    const float* __restrict__ seq, const float* __restrict__ Whh0,
    const float* __restrict__ Wih0, bf16_t* __restrict__ h0b,
    unsigned* __restrict__ flg0p, int g, int slot, int lane, int rbase,
    int rt, int c, float b0r, float b0z, float b0nx, float b0nh) {
  const int lm = lane & 15, lq = lane >> 4, koff = lq * 8;
  const int arow = rbase + rt * 16 + lm;

  bf16x8 f0[3][17];  // 51 frags, resident (VGPR+AGPR unified file)
#pragma unroll
  for (int gg = 0; gg < 3; ++gg) {
    const float* wh = Whh0 + (size_t)(gg * kH + c) * kH + koff;
#pragma unroll
    for (int kc = 0; kc < 16; ++kc) f0[gg][kc] = fragf(wh + kc * 32);
    f0[gg][16] = fragf(Wih0 + (size_t)(gg * kH + c) * kF + koff);
  }
  float h0m[4] = {0.f, 0.f, 0.f, 0.f};

  // producer store base in fragment-major layout
  const int kcb = slot >> 1;
  const int lq2 = ((slot & 1) << 1) | (lm >> 3);
  const int stoff = ((g * 2 + rt) * 16 + kcb) * 1024 +
                    ((lq2 << 4) + lq * 4) * 16 + (lm & 7) * 2;
  const int tbase = (g * 2 + rt) * 16 * 1024;

  for (int s = 0; s <= kT; ++s) {
    const int pr = (s + RING - 1) & (RING - 1), pw = s & (RING - 1);
    if (s < kT) {
      // seq prefetch first: flag-independent, oldest outstanding vmem
      const float* xp = seq + ((size_t)arow * kT + s) * kF + koff;
      float xs[8];
#pragma unroll
      for (int j = 0; j < 8; ++j) xs[j] = xp[j];
      // gate on h0[s-1] from all CUs of this group
      if (s > 0) poll_flags<XL>(flg0p, lane, (unsigned)s);
      if constexpr (XL) {
        if ((s & (RING - 1)) == 0) asm volatile("buffer_inv" ::: "memory");
      }
      f32x4 aR{0,0,0,0}, aZ{0,0,0,0}, aNH{0,0,0,0}, aNX{0,0,0,0};
      const char* hsrc = (const char*)h0b + pr * IMG + tbase + lane * 16;
      if constexpr (XL) {
        bf16x8 cA[4], cB[4];
        L0_ISSUE(cA, 0);
        L0_ISSUE(cB, 4);
        WAITVM(4);
        L0_MFMA(cA, 0);
        L0_ISSUE(cA, 8);
        WAITVM(4);
        L0_MFMA(cB, 4);
        L0_ISSUE(cB, 12);
        WAITVM(4);
        L0_MFMA(cA, 8);
        WAITVM(0);
        L0_MFMA(cB, 12);
      } else {
#pragma unroll
        for (int kc = 0; kc < 16; ++kc) {
          bf16x8 a = ld16_mall((const bf16_t*)(hsrc + kc * 1024));
          aR  = MFMA(a, f0[0][kc], aR, 0, 0, 0);
          aZ  = MFMA(a, f0[1][kc], aZ, 0, 0, 0);
          aNH = MFMA(a, f0[2][kc], aNH, 0, 0, 0);
        }
      }
      {
        bf16x8 ax;
#pragma unroll
        for (int j = 0; j < 8; ++j) ax[j] = (bf16_t)xs[j];
        aR  = MFMA(ax, f0[0][16], aR, 0, 0, 0);
        aZ  = MFMA(ax, f0[1][16], aZ, 0, 0, 0);
        aNX = MFMA(ax, f0[2][16], aNX, 0, 0, 0);
      }
      char* hnb = (char*)h0b + pw * IMG;
#pragma unroll
      for (int i = 0; i < 4; ++i) {
        float r = sigmoid_f(aR[i] + b0r);
        float z = sigmoid_f(aZ[i] + b0z);
        float n = tanh_f((aNX[i] + b0nx) + r * (aNH[i] + b0nh));
        float hn = (1.f - z) * n + z * h0m[i];
        h0m[i] = hn;
        st2x<XL>((bf16_t*)(hnb + stoff + i * 16), hn);
      }
      drain_stores();  // h0[s] in L2 before flagging
      if (lane == 0) flag_post<XL>(flg0p + rt * 32 + slot, (unsigned)(s + 1));
    }
    __syncthreads();  // P(s)
    if constexpr (!XL) __syncthreads();  // B (fallback keeps R16 structure)
  }
}

// ---- role: layer 1 h-part + epilogue + flag1 (wave 1) ----
template <bool XL>
__device__ __attribute__((noinline)) void role_l1h(
    const float* __restrict__ Whh1, bf16_t* __restrict__ h1b,
    float* __restrict__ h1f, unsigned* __restrict__ flg1p, int slot,
    float* part, int g, int lane, int rbase, int c,
    float b1r, float b1z, float b1nx, float b1nh) {
  const int lm = lane & 15, lq = lane >> 4, koff = lq * 8;
  bf16x8 fh[3][16];  // 48 frags
#pragma unroll
  for (int gg = 0; gg < 3; ++gg) {
    const float* wh = Whh1 + (size_t)(gg * kH + c) * kH + koff;
#pragma unroll
    for (int kc = 0; kc < 16; ++kc) fh[gg][kc] = fragf(wh + kc * 32);
  }
  float h1m[2][4] = {{0,0,0,0},{0,0,0,0}};

  const int kcb = slot >> 1;
  const int lq2 = ((slot & 1) << 1) | (lm >> 3);
  const int st0 = (g * 2 * 16 + kcb) * 1024 +
                  ((lq2 << 4) + lq * 4) * 16 + (lm & 7) * 2;
  const int tbase = g * 2 * 16 * 1024;

  for (int s = 0; s <= kT; ++s) {
    const int pr = (s + RING - 1) & (RING - 1), pw = s & (RING - 1);
    f32x4 cR[2], cZ[2], cNH[2];
#pragma unroll
    for (int rt = 0; rt < 2; ++rt) {
      cR[rt] = f32x4{0,0,0,0}; cZ[rt] = f32x4{0,0,0,0}; cNH[rt] = f32x4{0,0,0,0};
    }
    if (s >= 1) {
      poll_flags<XL>(flg1p, lane & 31, (unsigned)s);  // h1[s-1] from all CUs
      if constexpr (XL) {
        if ((s & (RING - 1)) == 0) asm volatile("buffer_inv" ::: "memory");
      }
      const char* hsrc = (const char*)h1b + pr * IMG + tbase + lane * 16;
      if constexpr (XL) {
        bf16x8 a0A[4], a1A[4], a0B[4], a1B[4];
        L1_ISSUE(a0A, a1A, 0);
        L1_ISSUE(a0B, a1B, 4);
        WAITVM(8);
        L1_MFMA(cR, cZ, cNH, fh, a0A, a1A, 0);
        L1_ISSUE(a0A, a1A, 8);
        WAITVM(8);
        L1_MFMA(cR, cZ, cNH, fh, a0B, a1B, 4);
        L1_ISSUE(a0B, a1B, 12);
        WAITVM(8);
        L1_MFMA(cR, cZ, cNH, fh, a0A, a1A, 8);
        WAITVM(0);
        L1_MFMA(cR, cZ, cNH, fh, a0B, a1B, 12);
      } else {
#pragma unroll
        for (int kc = 0; kc < 16; ++kc) {
          bf16x8 a0 = ld16_mall((const bf16_t*)(hsrc + kc * 1024));
          bf16x8 a1 = ld16_mall((const bf16_t*)(hsrc + 16384 + kc * 1024));
          cR[0]  = MFMA(a0, fh[0][kc], cR[0], 0,0,0);
          cR[1]  = MFMA(a1, fh[0][kc], cR[1], 0,0,0);
          cZ[0]  = MFMA(a0, fh[1][kc], cZ[0], 0,0,0);
          cZ[1]  = MFMA(a1, fh[1][kc], cZ[1], 0,0,0);
          cNH[0] = MFMA(a0, fh[2][kc], cNH[0],0,0,0);
          cNH[1] = MFMA(a1, fh[2][kc], cNH[1],0,0,0);
        }
      }
    }
    __syncthreads();  // P(s): w3's part[s&1] visible
    if (s >= 1) {
      float* pb = part + (s & 1) * PARTN;
      char* hnb = (char*)h1b + pw * IMG;
#pragma unroll
      for (int rt = 0; rt < 2; ++rt) {
        f32x4 pR  = LDSF4(pb + ((rt * 3 + 0) * 64 + lane) * 4);
        f32x4 pZ  = LDSF4(pb + ((rt * 3 + 1) * 64 + lane) * 4);
        f32x4 pNX = LDSF4(pb + ((rt * 3 + 2) * 64 + lane) * 4);
#pragma unroll
        for (int i = 0; i < 4; ++i) {
          float r = sigmoid_f(cR[rt][i] + pR[i] + b1r);
          float z = sigmoid_f(cZ[rt][i] + pZ[i] + b1z);
          float n = tanh_f((pNX[i] + b1nx) + r * (cNH[rt][i] + b1nh));
          float hn = (1.f - z) * n + z * h1m[rt][i];
          h1m[rt][i] = hn;
          if (s < kT) st2x<XL>((bf16_t*)(hnb + st0 + rt * 16384 + i * 16), hn);
          else        h1f[(rbase + rt * 16 + lq * 4 + i) * kH + c] = hn;
        }
      }
    }
    if (s < kT) {
      drain_stores();  // h1[s] in L2 before flagging
      if (lane == 0) flag_post<XL>(flg1p + slot, (unsigned)(s + 1));
    }
    if constexpr (!XL) {
      if (s < kT) poll_flags<XL>(flg1p, lane & 31, (unsigned)(s + 1));
      __syncthreads();  // B (fallback rendezvous)
    }
  }
}

// ---- role: layer 1 x-part -> LDS partials (wave 3) ----
template <bool XL>
__device__ __attribute__((noinline)) void role_l1x(
    const float* __restrict__ Wih1, bf16_t* __restrict__ h0b,
    float* part, unsigned* __restrict__ flg0p, int g, int lane, int c) {
  const int lq = lane >> 4, koff = lq * 8;
  bf16x8 fx[3][16];  // 48 frags
#pragma unroll
  for (int gg = 0; gg < 3; ++gg) {
    const float* wi = Wih1 + (size_t)(gg * kH + c) * kH + koff;
#pragma unroll
    for (int kc = 0; kc < 16; ++kc) fx[gg][kc] = fragf(wi + kc * 32);
  }
  const int tbase = g * 2 * 16 * 1024;

  for (int s = 0; s <= kT; ++s) {
    const int pr = (s + RING - 1) & (RING - 1);
    if (s >= 1) {
      poll_flags<XL>(flg0p, lane, (unsigned)s);  // h0[s-1] from all CUs
      if constexpr (XL) {
        if ((s & (RING - 1)) == 0) asm volatile("buffer_inv" ::: "memory");
      }
      f32x4 xR[2], xZ[2], xNX[2];
#pragma unroll
      for (int rt = 0; rt < 2; ++rt) {
        xR[rt] = f32x4{0,0,0,0}; xZ[rt] = f32x4{0,0,0,0}; xNX[rt] = f32x4{0,0,0,0};
      }
      const char* hsrc = (const char*)h0b + pr * IMG + tbase + lane * 16;
      if constexpr (XL) {
        bf16x8 a0A[4], a1A[4], a0B[4], a1B[4];
        L1_ISSUE(a0A, a1A, 0);
        L1_ISSUE(a0B, a1B, 4);
        WAITVM(8);
        L1_MFMA(xR, xZ, xNX, fx, a0A, a1A, 0);
        L1_ISSUE(a0A, a1A, 8);
        WAITVM(8);
        L1_MFMA(xR, xZ, xNX, fx, a0B, a1B, 4);
        L1_ISSUE(a0B, a1B, 12);
        WAITVM(8);
        L1_MFMA(xR, xZ, xNX, fx, a0A, a1A, 8);
        WAITVM(0);
        L1_MFMA(xR, xZ, xNX, fx, a0B, a1B, 12);
      } else {
#pragma unroll
        for (int kc = 0; kc < 16; ++kc) {
          bf16x8 a0 = ld16_mall((const bf16_t*)(hsrc + kc * 1024));
          bf16x8 a1 = ld16_mall((const bf16_t*)(hsrc + 16384 + kc * 1024));
          xR[0]  = MFMA(a0, fx[0][kc], xR[0], 0,0,0);
          xR[1]  = MFMA(a1, fx[0][kc], xR[1], 0,0,0);
          xZ[0]  = MFMA(a0, fx[1][kc], xZ[0], 0,0,0);
          xZ[1]  = MFMA(a1, fx[1][kc], xZ[1], 0,0,0);
          xNX[0] = MFMA(a0, fx[2][kc], xNX[0],0,0,0);
          xNX[1] = MFMA(a1, fx[2][kc], xNX[1],0,0,0);
        }
      }
      float* pb = part + (s & 1) * PARTN;
#pragma unroll
      for (int rt = 0; rt < 2; ++rt) {
        LDSF4(pb + ((rt * 3 + 0) * 64 + lane) * 4) = xR[rt];
        LDSF4(pb + ((rt * 3 + 1) * 64 + lane) * 4) = xZ[rt];
        LDSF4(pb + ((rt * 3 + 2) * 64 + lane) * 4) = xNX[rt];
      }
    }
    __syncthreads();  // P(s)
    if constexpr (!XL) __syncthreads();  // B
  }
}

__launch_bounds__(NTHR, 1)
__global__ void gru_persistent(
    const float* __restrict__ seq,
    const float* __restrict__ Wih0, const float* __restrict__ Whh0,
    const float* __restrict__ bih0, const float* __restrict__ bhh0,
    const float* __restrict__ Wih1, const float* __restrict__ Whh1,
    const float* __restrict__ bih1, const float* __restrict__ bhh1,
    char* __restrict__ ws) {
  extern __shared__ char smem[];
  float* part = (float*)(smem + PART_OFF);
  __shared__ unsigned sh_enc;

  const int tid = threadIdx.x;

  // ---- self-organization: group = physical XCD, slot = per-XCD ordinal ----
  if (tid == 0) {
    unsigned xcd;
    asm("s_getreg_b32 %0, hwreg(HW_REG_XCC_ID)" : "=s"(xcd));
    xcd &= 7;
    unsigned* cnt   = (unsigned*)(ws + WS_CNT) + xcd * 32;
    unsigned* total = (unsigned*)(ws + WS_TOTAL);
    unsigned* fb    = (unsigned*)(ws + WS_FB);
    unsigned slot = __hip_atomic_fetch_add(cnt, 1u, __ATOMIC_RELAXED,
                                           __HIP_MEMORY_SCOPE_AGENT);
    if (slot >= 32)
      __hip_atomic_store(fb, 1u, __ATOMIC_RELAXED, __HIP_MEMORY_SCOPE_AGENT);
    __hip_atomic_fetch_add(total, 1u, __ATOMIC_RELAXED,
                           __HIP_MEMORY_SCOPE_AGENT);
    long guard = 0;
    while (__hip_atomic_load(total, __ATOMIC_RELAXED,
                             __HIP_MEMORY_SCOPE_AGENT) < (unsigned)GBLK) {
      __builtin_amdgcn_s_sleep(1);  // one-time startup
      if (++guard > (1L << 24)) break;
    }
    unsigned f = __hip_atomic_load(fb, __ATOMIC_RELAXED,
                                   __HIP_MEMORY_SCOPE_AGENT);
    sh_enc = (f << 31) | (xcd << 8) | (slot & 255);
  }
  __syncthreads();
  const unsigned enc = sh_enc;
  const bool fallback = (enc >> 31) != 0;
  const int g    = fallback ? (blockIdx.x & 7)  : (int)((enc >> 8) & 7);
  const int slot = fallback ? (blockIdx.x >> 3) : (int)(enc & 255);
  const int hs   = slot * HB;

  const int lm = tid & 15;
  const int c = hs + lm;
  const float b0r  = bih0[c] + bhh0[c];
  const float b0z  = bih0[kH + c] + bhh0[kH + c];
  const float b0nx = bih0[2 * kH + c];
  const float b0nh = bhh0[2 * kH + c];
  const float b1r  = bih1[c] + bhh1[c];
  const float b1z  = bih1[kH + c] + bhh1[kH + c];
  const float b1nx = bih1[2 * kH + c];
  const float b1nh = bhh1[2 * kH + c];

  bf16_t* h0b = (bf16_t*)(ws + WS_H0B);
  bf16_t* h1b = (bf16_t*)(ws + WS_H1B);
  float*  h1f = (float*)(ws + WS_H1F);
  unsigned* flg1p = (unsigned*)(ws + WS_FLG1) + g * 32;  // 128B/group
  unsigned* flg0p = (unsigned*)(ws + WS_FLG0) + g * 64;  // 256B/group
  const int wv   = tid >> 6;
  const int lane = tid & 63;
  const int rbase = g * RG;

  if (!fallback) {
    if (wv == 0)
      role_l0<true>(seq, Whh0, Wih0, h0b, flg0p, g, slot, lane, rbase, 0, c,
                    b0r, b0z, b0nx, b0nh);
    else if (wv == 2)
      role_l0<true>(seq, Whh0, Wih0, h0b, flg0p, g, slot, lane, rbase, 1, c,
                    b0r, b0z, b0nx, b0nh);
    else if (wv == 1)
      role_l1h<true>(Whh1, h1b, h1f, flg1p, slot, part, g, lane, rbase, c,
                     b1r, b1z, b1nx, b1nh);
    else
      role_l1x<true>(Wih1, h0b, part, flg0p, g, lane, c);
  } else {
    if (wv == 0)
      role_l0<false>(seq, Whh0, Wih0, h0b, flg0p, g, slot, lane, rbase, 0, c,
                     b0r, b0z, b0nx, b0nh);
    else if (wv == 2)
      role_l0<false>(seq, Whh0, Wih0, h0b, flg0p, g, slot, lane, rbase, 1, c,
                     b0r, b0z, b0nx, b0nh);
    else if (wv == 1)
      role_l1h<false>(Whh1, h1b, h1f, flg1p, slot, part, g, lane, rbase, c,
                      b1r, b1z, b1nx, b1nh);
    else
      role_l1x<false>(Wih1, h0b, part, flg0p, g, lane, c);
  }
}

// ---- head: concat(h1_last, embed) -> fc1+relu -> fc2 ----
__global__ void head_kernel(const float* __restrict__ h1,
                            const int* __restrict__ ticker,
                            const float* __restrict__ etab,
                            const float* __restrict__ fc1w,
                            const float* __restrict__ fc1b,
                            const float* __restrict__ fc2w,
                            const float* __restrict__ fc2b,
                            float* __restrict__ out) {
  __shared__ float xin[4][kH + kE];
  __shared__ float y1[4][kH];
  const int tid = threadIdx.x;
  const int b0 = blockIdx.x * 4;

  for (int idx = tid; idx < 4 * (kH + kE); idx += 256) {
    const int r = idx / (kH + kE), k = idx % (kH + kE);
    const int b = b0 + r;
    xin[r][k] = (k < kH) ? h1[b * kH + k] : etab[ticker[b] * kE + (k - kH)];
  }
  __syncthreads();

#pragma unroll
  for (int jj = 0; jj < 2; ++jj) {
    const int j = tid + jj * 256;
    const float* wr = fc1w + j * (kH + kE);
    float a0 = 0.f, a1 = 0.f, a2 = 0.f, a3 = 0.f;
    for (int k = 0; k < kH + kE; ++k) {
      const float w = wr[k];
      a0 += w * xin[0][k];
      a1 += w * xin[1][k];
      a2 += w * xin[2][k];
      a3 += w * xin[3][k];
    }
    const float bb = fc1b[j];
    y1[0][j] = fmaxf(a0 + bb, 0.f);
    y1[1][j] = fmaxf(a1 + bb, 0.f);
    y1[2][j] = fmaxf(a2 + bb, 0.f);
    y1[3][j] = fmaxf(a3 + bb, 0.f);
  }
  __syncthreads();

  if (tid < 4 * kPD) {
    const int r = tid / kPD, j = tid % kPD;
    const float* wr = fc2w + j * kH;
    float acc = fc2b[j];
    for (int k = 0; k < kH; ++k) acc += wr[k] * y1[r][k];
    out[(b0 + r) * kPD + j] = acc;
  }
}

extern "C" void kernel_launch(void* const* d_in, const int* in_sizes, int n_in,
                              void* d_out, int out_size, void* d_ws,
                              size_t ws_size, hipStream_t stream) {
  (void)in_sizes; (void)n_in; (void)out_size; (void)ws_size;

  const int*   ticker = (const int*)d_in[0];
  const float* seq    = (const float*)d_in[1];
  const float* etab   = (const float*)d_in[2];
  const float* Wih0   = (const float*)d_in[3];
  const float* Whh0   = (const float*)d_in[4];
  const float* bih0   = (const float*)d_in[5];
  const float* bhh0   = (const float*)d_in[6];
  const float* Wih1   = (const float*)d_in[7];
  const float* Whh1   = (const float*)d_in[8];
  const float* bih1   = (const float*)d_in[9];
  const float* bhh1   = (const float*)d_in[10];
  const float* fc1w   = (const float*)d_in[11];
  const float* fc1b   = (const float*)d_in[12];
  const float* fc2w   = (const float*)d_in[13];
  const float* fc2b   = (const float*)d_in[14];

  char* ws = (char*)d_ws;
  (void)hipMemsetAsync(ws, 0, WS_INIT, stream);  // counters+flags+both rings

  gru_persistent<<<GBLK, NTHR, LDSB, stream>>>(
      seq, Wih0, Whh0, bih0, bhh0, Wih1, Whh1, bih1, bhh1, ws);

  head_kernel<<<kB / 4, 256, 0, stream>>>((const float*)(ws + WS_H1F), ticker,
                                          etab, fc1w, fc1b, fc2w, fc2b,
                                          (float*)d_out);
}